// Round 3
// baseline (2023.813 us; speedup 1.0000x reference)
//
#include <hip/hip_runtime.h>
#include <hip/hip_cooperative_groups.h>
#include <hip/hip_bf16.h>
#include <stdint.h>
#include <math.h>

namespace cg = cooperative_groups;

typedef uint32_t u32;
typedef __hip_bfloat16 bf16t;
typedef __attribute__((ext_vector_type(8))) short short8;
typedef __attribute__((ext_vector_type(4))) float f32x4;

// JAX PRNG: threefry2x32, jax_threefry_partitionable=True semantics (verified R2):
//   split(key,n)[i] = (o0(key;0,i), o1(key;0,i))
//   random_bits32(key,shape)[f] = o0(key;0,f) ^ o1(key;0,f)
//   randint pre-splits its key, uses subkey2; span 8192 pow2 -> bits & 8191
//   fold_in(key,d) = threefry(key,(0,d))

// ================= threefry2x32 (bit-exact vs JAX) =================
__host__ __device__ __forceinline__ void tf2(u32 k0, u32 k1, u32 c0, u32 c1, u32& o0, u32& o1) {
  const u32 ks2 = k0 ^ k1 ^ 0x1BD11BDAu;
  u32 x0 = c0 + k0, x1 = c1 + k1;
#define TFROT(v,r) (((v)<<(r))|((v)>>(32-(r))))
#define TFR(r) { x0 += x1; x1 = TFROT(x1,r); x1 ^= x0; }
  TFR(13) TFR(15) TFR(26) TFR(6)   x0 += k1;  x1 += ks2 + 1u;
  TFR(17) TFR(29) TFR(16) TFR(24)  x0 += ks2; x1 += k0 + 2u;
  TFR(13) TFR(15) TFR(26) TFR(6)   x0 += k0;  x1 += k1 + 3u;
  TFR(17) TFR(29) TFR(16) TFR(24)  x0 += k1;  x1 += ks2 + 4u;
  TFR(13) TFR(15) TFR(26) TFR(6)   x0 += ks2; x1 += k0 + 5u;
#undef TFR
#undef TFROT
  o0 = x0; o1 = x1;
}

__device__ __forceinline__ float unif_row(u32 ka, u32 kb, int i) {
  u32 o0, o1;
  tf2(ka, kb, 0u, (u32)i, o0, o1);
  return __uint_as_float(0x3F800000u | ((o0 ^ o1) >> 9)) - 1.0f;
}

__device__ __forceinline__ int ridx_fn(u32 ka, u32 kb, u32 f) {
  u32 o0, o1; tf2(ka, kb, 0u, f, o0, o1); return (int)((o0 ^ o1) & 8191u);
}

static inline void split2(u32 ka, u32 kb, u32* kA, u32* kB) {
  u32 a0, a1, b0, b1;
  tf2(ka, kb, 0u, 0u, a0, a1);
  tf2(ka, kb, 0u, 1u, b0, b1);
  kA[0] = a0; kA[1] = a1; kB[0] = b0; kB[1] = b1;
}

static inline void split6(u32 ka, u32 kb, u32 out[6][2]) {
  for (u32 i = 0; i < 6; i++) { u32 o0, o1; tf2(ka, kb, 0u, i, o0, o1); out[i][0] = o0; out[i][1] = o1; }
}

static inline int scalar_randint8192(u32 ka, u32 kb) {
  u32 kA[2], kB[2];
  split2(ka, kb, kA, kB);
  u32 o0, o1;
  tf2(kB[0], kB[1], 0u, 0u, o0, o1);
  return (int)((o0 ^ o1) & 8191u);
}

__device__ __forceinline__ ushort f2bf(float f) {  // f32 -> bf16 RNE
  u32 u = __float_as_uint(f);
  u32 r = u + 0x7FFFu + ((u >> 16) & 1u);
  return (ushort)(r >> 16);
}

// ================= fused packing kernel =================
// job A (blocks [0,32768)):   pack adj f32 -> bf16 GEMM A-tile image:
//   chunk (cm=m>>7, s=k>>6) is 16KB, the exact LDS image of one 128x64 tile:
//   unit(16B) = r*8 + (kq ^ (r&7)), r=m&127, kq=(k&63)>>3. The XOR bakes the
//   LDS bank-swizzle into the packed layout so global_load_lds stages linearly.
// job B (blocks [32768,36864)): pack input f32 [8192][1024] -> k-group-major bf16
// job C (blocks [36864,37376)): pack weight f32 [1024][1024] -> k-group-major bf16
__device__ __forceinline__ void packa_body(int idx, const float* __restrict__ A, uint4* __restrict__ out,
                                           int K, int lgS) {
  const int S = K >> 6;
  const int chunk = idx >> 10;
  const int w = idx & 1023;
  const int r = w >> 3, kq = w & 7;
  const int cm = chunk >> lgS, s = chunk & (S - 1);
  const float* src = A + (size_t)((cm << 7) + r) * K + (s << 6) + (kq << 3);
  const float4 f0 = *(const float4*)src;
  const float4 f1 = *(const float4*)(src + 4);
  u32 wv[4];
  wv[0] = (u32)f2bf(f0.x) | ((u32)f2bf(f0.y) << 16);
  wv[1] = (u32)f2bf(f0.z) | ((u32)f2bf(f0.w) << 16);
  wv[2] = (u32)f2bf(f1.x) | ((u32)f2bf(f1.y) << 16);
  wv[3] = (u32)f2bf(f1.z) | ((u32)f2bf(f1.w) << 16);
  uint4 o; o.x = wv[0]; o.y = wv[1]; o.z = wv[2]; o.w = wv[3];
  out[((size_t)chunk << 10) + (r << 3) + (kq ^ (r & 7))] = o;
}

__device__ __forceinline__ void packb_body(int idx, const float* __restrict__ B, uint4* __restrict__ out,
                                           int Nn) {
  const int g = idx / Nn;
  const int n = idx - g * Nn;
  u32 wv[4];
#pragma unroll
  for (int j = 0; j < 4; j++) {
    const float f0 = B[(size_t)(g * 8 + 2 * j) * Nn + n];
    const float f1 = B[(size_t)(g * 8 + 2 * j + 1) * Nn + n];
    wv[j] = (u32)f2bf(f0) | ((u32)f2bf(f1) << 16);
  }
  uint4 o; o.x = wv[0]; o.y = wv[1]; o.z = wv[2]; o.w = wv[3];
  out[idx] = o;
}

__global__ __launch_bounds__(256) void pack_all_k(
    const float* __restrict__ adj, uint4* __restrict__ apk,
    const float* __restrict__ inp, uint4* __restrict__ b1p,
    const float* __restrict__ wgt, uint4* __restrict__ wp) {
  const int b = blockIdx.x;
  const int tid = threadIdx.x;
  if (b < 32768) {
    packa_body(b * 256 + tid, adj, apk, 8192, 7);          // 32768*256 units exactly
  } else if (b < 36864) {
    packb_body((b - 32768) * 256 + tid, inp, b1p, 1024);   // (8192/8)*1024 = 4096*256
  } else {
    packb_body((b - 36864) * 256 + tid, wgt, wp, 1024);    // (1024/8)*1024 = 512*256
  }
}

// ================= bf16 MFMA GEMM — m97 structure =================
// 256 threads / 4 waves, 2x2 wave grid of 64x64 tiles (acc[4][4]), BM=BN=128,
// BK=64, both operands staged via global_load_lds (A pre-packed+swizzled,
// B k-group-major), double-buffered LDS (64KB -> 2 blocks/CU), 1 barrier/step.
__device__ __forceinline__ void gld_lds16(const void* g, void* l) {
  __builtin_amdgcn_global_load_lds((const __attribute__((address_space(1))) void*)g,
                                   (__attribute__((address_space(3))) void*)l, 16, 0, 0);
}

// EPI 1: C = (1-alpha)*acc + alpha*aux, + fused block min/max -> prt
// EPI 2: C = theta*acc + (1-theta)*aux, theta = log(lamda/l + 1)
// Grid: bm = blockIdx&63 (XCD = bm&7), bn = blockIdx>>6 — n-blocks of an A-panel
// share one XCD's L2.
template <int EPI>
__global__ __launch_bounds__(256, 2) void gemm_k(
    const bf16t* __restrict__ Ap, const bf16t* __restrict__ Bp,
    const float* __restrict__ aux, const float* __restrict__ sF,
    const int* __restrict__ sI, float* __restrict__ C,
    float* __restrict__ prt, int PG, int Nn, int K) {
  __shared__ __align__(16) bf16t As[2][8192];
  __shared__ __align__(16) bf16t Bs[2][8192];
  const int tid = threadIdx.x;
  const int lane = tid & 63;
  const int wave = tid >> 6;                 // 0..3
  const int bm = blockIdx.x & 63;
  const int bn = blockIdx.x >> 6;
  const int m0 = bm << 7, n0 = bn << 7;
  const int wm = (wave & 1) << 6;            // 0,64
  const int wn = (wave >> 1) << 6;           // 0,64
  const int S = K >> 6;

  f32x4 acc[4][4];
#pragma unroll
  for (int i = 0; i < 4; i++)
#pragma unroll
    for (int j = 0; j < 4; j++) acc[i][j] = (f32x4){0.f, 0.f, 0.f, 0.f};

  // staging: 1024 16B-units per tile; thread t owns units t + j*256, j=0..3
  const bf16t* gA0 = Ap + (((size_t)bm * S) << 13);  // chunk (bm,s): 8192 bf16
  const bf16t* gBj[4];
  const size_t bstep = (size_t)Nn * 64;              // B elems per super-step
#pragma unroll
  for (int j = 0; j < 4; j++) {
    const int u = tid + (j << 8);
    gBj[j] = Bp + ((size_t)(u >> 7) * Nn + n0 + (u & 127)) * 8;
  }
  auto stage = [&](int s, int buf) {
    const bf16t* a = gA0 + ((size_t)s << 13);
#pragma unroll
    for (int j = 0; j < 4; j++) {
      const int u = tid + (j << 8);
      gld_lds16(a + ((size_t)u << 3), &As[buf][u << 3]);
    }
#pragma unroll
    for (int j = 0; j < 4; j++) {
      const int u = tid + (j << 8);
      gld_lds16(gBj[j] + (size_t)s * bstep, &Bs[buf][u << 3]);
    }
  };

  // frag read bases (bf16-element indices)
  const int arow = lane & 15, aq = lane >> 4;
  // A: elem = row*64 + ((kq ^ (row&7))<<3), row = wm+mt*16+arow, kq = c*4+aq
  const int abase = ((wm + arow) << 6) + ((aq ^ (arow & 7)) << 3);
  // B: elem = (kg*128 + col)*8, kg = c*4+aq, col = wn+nt*16+arow
  const int bbase = ((aq << 7) + wn + arow) << 3;

  stage(0, 0);

  for (int s = 0; s < S; ++s) {
    const int cur = s & 1;
    __syncthreads();  // drains step-s prefetch (vmcnt), publishes buf[cur]
    if (s + 1 < S) stage(s + 1, cur ^ 1);
#pragma unroll
    for (int c = 0; c < 2; ++c) {
      short8 af[4], bv[4];
      const int ab = abase ^ (c << 5);
#pragma unroll
      for (int mt = 0; mt < 4; mt++)
        af[mt] = *(const short8*)(&As[cur][ab + mt * 1024]);
#pragma unroll
      for (int nt = 0; nt < 4; nt++)
        bv[nt] = *(const short8*)(&Bs[cur][bbase + (c << 12) + (nt << 7)]);
#pragma unroll
      for (int mt = 0; mt < 4; mt++)
#pragma unroll
        for (int nt = 0; nt < 4; nt++)
          acc[mt][nt] = __builtin_amdgcn_mfma_f32_16x16x32_bf16(af[mt], bv[nt], acc[mt][nt], 0, 0, 0);
    }
  }

  float p1, p2;
  if (EPI == 1) { const float al = sF[0]; p1 = 1.0f - al; p2 = al; }
  else { const float th = logf(sF[0] / (float)sI[0] + 1.0f); p1 = th; p2 = 1.0f - th; }
  const int col = lane & 15, rq = lane >> 4;
  float vlo = 3.4e38f, vhi = -3.4e38f;
#pragma unroll
  for (int mt = 0; mt < 4; mt++)
#pragma unroll
    for (int nt = 0; nt < 4; nt++)
#pragma unroll
      for (int r = 0; r < 4; r++) {
        const int gm = m0 + wm + mt * 16 + (rq << 2) + r;
        const int gn = n0 + wn + nt * 16 + col;
        const size_t ix = (size_t)gm * Nn + gn;
        const float v = p1 * acc[mt][nt][r] + p2 * aux[ix];
        C[ix] = v;
        if (EPI == 1) { vlo = fminf(vlo, v); vhi = fmaxf(vhi, v); }
      }
  if (EPI == 1) {  // fused block min/max -> partials
    __syncthreads();
    float* red = (float*)&As[0][0];
    red[tid] = vlo; red[256 + tid] = vhi;
    __syncthreads();
    for (int s = 128; s > 0; s >>= 1) {
      if (tid < s) {
        red[tid] = fminf(red[tid], red[tid + s]);
        red[256 + tid] = fmaxf(red[256 + tid], red[256 + tid + s]);
      }
      __syncthreads();
    }
    if (tid == 0) { prt[blockIdx.x] = red[0]; prt[PG + blockIdx.x] = red[256]; }
  }
}

// ================= whale optimizer: all 10 iterations, one cooperative kernel =================
struct WA {
  u32 k1a, k1b, k2a, k2b, k3a, k3b, k4a, k4b, k5a, k5b;
  int ldr;
  float a, a2;
};
struct WAll { WA w[10]; };

// Grid 1024x256 (4 blocks/CU co-resident via __launch_bounds__(256,4) — well
// under coop capacity). 1 wave = 1 row, 2 rows/wave, 8 rows/block -> 8192 rows.
// All branches are row-uniform (wave-uniform). 9 grid.sync() between iterations.
// Prologue: every block redundantly reduces the 512+512 gemm1 partials -> lo/hi.
// Iteration 9 writes ONLY the packed-bf16 OPT image (f32 ping-pong write skipped).
__global__ __launch_bounds__(256, 4) void whale_all_k(
    const float* __restrict__ sup, float* __restrict__ p0, float* __restrict__ p1,
    ushort* __restrict__ opt, const float* __restrict__ prt, WAll wall) {
  __shared__ float slo[256], shi[256];
  const int tid = threadIdx.x;
  {
    float l = fminf(prt[tid], prt[tid + 256]);
    float h = fmaxf(prt[512 + tid], prt[768 + tid]);
    slo[tid] = l; shi[tid] = h; __syncthreads();
    for (int s = 128; s > 0; s >>= 1) {
      if (tid < s) { slo[tid] = fminf(slo[tid], slo[tid + s]); shi[tid] = fmaxf(shi[tid], shi[tid + s]); }
      __syncthreads();
    }
  }
  const float lo = slo[0], hi = shi[0];

  cg::grid_group grid = cg::this_grid();
  const int wave = tid >> 6, lane = tid & 63;
  const int rbase = blockIdx.x * 8 + wave * 2;
  const float* cur = sup;
  for (int it = 0; it < 10; ++it) {
    float* nxt = (it & 1) ? p1 : p0;
    const WA w = wall.w[it];
    const float* ldp = cur + ((size_t)w.ldr << 10);
#pragma unroll
    for (int rr = 0; rr < 2; ++rr) {
      const int row = rbase + rr;
      // per-row randoms: every lane computes its own copy (wave-uniform values)
      const float r1 = unif_row(w.k1a, w.k1b, row);
      const float r2 = unif_row(w.k2a, w.k2b, row);
      const float u3 = unif_row(w.k3a, w.k3b, row);
      const float p  = unif_row(w.k4a, w.k4b, row);
      // A feeds the |A|>=1 branch: match XLA's mul-then-sub (no fma contraction)
      float t2 = (2.0f * w.a) * r1;
      asm volatile("" : "+v"(t2));
      const float A = t2 - w.a;
      const float Cc = 2.0f * r2;
      const float* pin = cur + ((size_t)row << 10);
      float* pout = nxt + ((size_t)row << 10);
      const bool bp = (p < 0.5f);
      const bool ex = bp && (fabsf(A) >= 1.0f);
      float s1 = 0.f, s2 = 0.f;
      if (!bp) {
        const float lp = (w.a2 - 1.0f) * u3 + 1.0f;
        s1 = expf(lp);
        s2 = cosf(6.2831855f * lp);
      }
#pragma unroll
      for (int k = 0; k < 4; ++k) {
        const int j0 = (lane + (k << 6)) << 2;   // element base of this float4
        float4 pv = *(const float4*)(pin + j0);
        float ov[4];
        if (ex) {  // explore: per-element random-row gather
          const u32 fb = ((u32)row << 10) + (u32)j0;
#pragma unroll
          for (int e = 0; e < 4; ++e) {
            const float pos = (&pv.x)[e];
            const int ri = ridx_fn(w.k5a, w.k5b, fb + (u32)e);
            const float xr = cur[((size_t)ri << 10) + j0 + e];
            ov[e] = fabsf(xr - A * fabsf(Cc * xr - pos));
          }
        } else {
          float4 lv = *(const float4*)(ldp + j0);
          if (bp) {  // exploit
#pragma unroll
            for (int e = 0; e < 4; ++e) {
              const float pos = (&pv.x)[e], ld = (&lv.x)[e];
              ov[e] = fabsf(ld - A * fabsf(Cc * ld - pos));
            }
          } else {  // spiral
#pragma unroll
            for (int e = 0; e < 4; ++e) {
              const float pos = (&pv.x)[e], ld = (&lv.x)[e];
              ov[e] = fabsf(fabsf(ld - pos) * s1 * s2 + ld);
            }
          }
        }
        float4 res;
#pragma unroll
        for (int e = 0; e < 4; ++e) (&res.x)[e] = fminf(fmaxf(ov[e], lo), hi);
        if (it != 9) {
          *(float4*)(pout + j0) = res;
        } else {
          // final positions straight into the packed-A image for gemm_k<2>
          // (K=1024 -> S=16): chunk = (row>>7)*16 + (j0>>6), elem in chunk =
          // (row&127)*64 + ((kq ^ (row&7))<<3) + (j0&7), kq = (j0>>3)&7
          ushort4 o4;
          o4.x = f2bf(res.x); o4.y = f2bf(res.y); o4.z = f2bf(res.z); o4.w = f2bf(res.w);
          const int rw = row & 127;
          const size_t chunk = (size_t)((row >> 7) << 4) + (j0 >> 6);
          ushort* dst = opt + (chunk << 13) + (rw << 6) + ((((j0 >> 3) & 7) ^ (rw & 7)) << 3) + (j0 & 7);
          *(ushort4*)dst = o4;
        }
      }
    }
    if (it < 9) grid.sync();
    cur = nxt;
  }
}

// ================= host =================
extern "C" void kernel_launch(void* const* d_in, const int* in_sizes, int n_in,
                              void* d_out, int out_size, void* d_ws, size_t ws_size,
                              hipStream_t stream) {
  const float* inp = (const float*)d_in[0];   // input  [8192,1024]
  const float* adj = (const float*)d_in[1];   // adj    [8192,8192]
  const float* h0  = (const float*)d_in[2];   // h0     [8192,1024]
  const float* wgt = (const float*)d_in[3];   // weight [1024,1024]
  const float* lam = (const float*)d_in[4];   // lamda scalar
  const float* alp = (const float*)d_in[5];   // alpha scalar
  const int* lint  = (const int*)d_in[6];     // l scalar

  float* outp = (float*)d_out;

  char* ws = (char*)d_ws;
  // Apk (134.2MB) lives at ws+0 and is dead after gemm1; the whale ping/pong and
  // packed OPT overlay it afterwards (stream-ordered, no overlap in time).
  bf16t* Apk  = (bf16t*)(ws);               // 134.2MB packed adj (dead after gemm1)
  float* P0   = (float*)(ws);               // 33.6MB whale ping   (overlays Apk)
  float* P1   = (float*)(ws + 33554432);    // 33.6MB whale pong   (overlays Apk)
  ushort* OPT = (ushort*)(ws + 67108864);   // 16.8MB final positions, packed-A image
  bf16t* B1p  = (bf16t*)(ws + 134217728);   // 16.8MB packed input
  bf16t* Wp   = (bf16t*)(ws + 150994944);   // 2.1MB packed weight
  float* SUP  = (float*)(ws + 153092096);   // 33.6MB support (live to the end)
  float* PRT  = (float*)(ws + 186646528);   // partials (512 lo + 512 hi)

  // 1) pack adj (A-tile image, swizzled) + input + weight — single kernel
  hipLaunchKernelGGL(pack_all_k, dim3(37376), dim3(256), 0, stream,
                     adj, (uint4*)Apk, inp, (uint4*)B1p, wgt, (uint4*)Wp);
  // 2) support = (1-alpha)*(adj@input) + alpha*h0, + fused min/max partials
  hipLaunchKernelGGL((gemm_k<1>), dim3(512), dim3(256), 0, stream, Apk, B1p, h0, alp, lint,
                     SUP, PRT, 512, 1024, 8192);

  // 3) whale optimizer, all 10 iterations in one cooperative kernel.
  //    key(42) = (0,42); split -> (k0, loop_key); leader chain precomputed host-side.
  u32 k0k[2], lpk[2];
  split2(0u, 42u, k0k, lpk);
  int ldr = scalar_randint8192(k0k[0], k0k[1]);
  WAll wall;
  for (int it = 0; it < 10; ++it) {
    u32 ka, kb; tf2(lpk[0], lpk[1], 0u, (u32)it, ka, kb);  // fold_in(loop_key, it)
    u32 ks[6][2];
    split6(ka, kb, ks);
    u32 k5A[2], k5B[2];
    split2(ks[4][0], ks[4][1], k5A, k5B);  // randint pre-split: use subkey2
    WA& w = wall.w[it];
    w.k1a = ks[0][0]; w.k1b = ks[0][1];
    w.k2a = ks[1][0]; w.k2b = ks[1][1];
    w.k3a = ks[2][0]; w.k3b = ks[2][1];
    w.k4a = ks[3][0]; w.k4b = ks[3][1];
    w.k5a = k5B[0];   w.k5b = k5B[1];
    w.ldr = ldr;
    const float itf = (float)it;
    w.a = 2.0f - itf * 0.2f;
    w.a2 = -1.0f + itf * (-0.1f);
    ldr = scalar_randint8192(ks[5][0], ks[5][1]);  // leader index for next iter
  }
  {
    const float* a0 = SUP; float* a1 = P0; float* a2 = P1; ushort* a3 = OPT;
    const float* a4 = PRT;
    void* wargs[] = {(void*)&a0, (void*)&a1, (void*)&a2, (void*)&a3, (void*)&a4, (void*)&wall};
    hipLaunchCooperativeKernel(whale_all_k, dim3(1024), dim3(256), wargs, 0, stream);
  }

  // 4) out = theta*(opt@weight) + (1-theta)*support
  hipLaunchKernelGGL((gemm_k<2>), dim3(512), dim3(256), 0, stream, (const bf16t*)OPT, Wp, SUP, lam, lint,
                     outp, (float*)nullptr, 0, 1024, 1024);
  (void)in_sizes; (void)n_in; (void)out_size; (void)ws_size;
}

// Round 4
// 869.841 us; speedup vs baseline: 2.3266x; 2.3266x over previous
//
#include <hip/hip_runtime.h>
#include <hip/hip_bf16.h>
#include <stdint.h>
#include <math.h>

typedef uint32_t u32;
typedef __hip_bfloat16 bf16t;
typedef __attribute__((ext_vector_type(8))) short short8;
typedef __attribute__((ext_vector_type(4))) float f32x4;

// JAX PRNG: threefry2x32, jax_threefry_partitionable=True semantics (verified R2):
//   split(key,n)[i] = (o0(key;0,i), o1(key;0,i))
//   random_bits32(key,shape)[f] = o0(key;0,f) ^ o1(key;0,f)
//   randint pre-splits its key, uses subkey2; span 8192 pow2 -> bits & 8191
//   fold_in(key,d) = threefry(key,(0,d))

// ================= threefry2x32 (bit-exact vs JAX) =================
__host__ __device__ __forceinline__ void tf2(u32 k0, u32 k1, u32 c0, u32 c1, u32& o0, u32& o1) {
  const u32 ks2 = k0 ^ k1 ^ 0x1BD11BDAu;
  u32 x0 = c0 + k0, x1 = c1 + k1;
#define TFROT(v,r) (((v)<<(r))|((v)>>(32-(r))))
#define TFR(r) { x0 += x1; x1 = TFROT(x1,r); x1 ^= x0; }
  TFR(13) TFR(15) TFR(26) TFR(6)   x0 += k1;  x1 += ks2 + 1u;
  TFR(17) TFR(29) TFR(16) TFR(24)  x0 += ks2; x1 += k0 + 2u;
  TFR(13) TFR(15) TFR(26) TFR(6)   x0 += k0;  x1 += k1 + 3u;
  TFR(17) TFR(29) TFR(16) TFR(24)  x0 += k1;  x1 += ks2 + 4u;
  TFR(13) TFR(15) TFR(26) TFR(6)   x0 += ks2; x1 += k0 + 5u;
#undef TFR
#undef TFROT
  o0 = x0; o1 = x1;
}

__device__ __forceinline__ float unif_row(u32 ka, u32 kb, int i) {
  u32 o0, o1;
  tf2(ka, kb, 0u, (u32)i, o0, o1);
  return __uint_as_float(0x3F800000u | ((o0 ^ o1) >> 9)) - 1.0f;
}

__device__ __forceinline__ int ridx_fn(u32 ka, u32 kb, u32 f) {
  u32 o0, o1; tf2(ka, kb, 0u, f, o0, o1); return (int)((o0 ^ o1) & 8191u);
}

static inline void split2(u32 ka, u32 kb, u32* kA, u32* kB) {
  u32 a0, a1, b0, b1;
  tf2(ka, kb, 0u, 0u, a0, a1);
  tf2(ka, kb, 0u, 1u, b0, b1);
  kA[0] = a0; kA[1] = a1; kB[0] = b0; kB[1] = b1;
}

static inline void split6(u32 ka, u32 kb, u32 out[6][2]) {
  for (u32 i = 0; i < 6; i++) { u32 o0, o1; tf2(ka, kb, 0u, i, o0, o1); out[i][0] = o0; out[i][1] = o1; }
}

static inline int scalar_randint8192(u32 ka, u32 kb) {
  u32 kA[2], kB[2];
  split2(ka, kb, kA, kB);
  u32 o0, o1;
  tf2(kB[0], kB[1], 0u, 0u, o0, o1);
  return (int)((o0 ^ o1) & 8191u);
}

__device__ __forceinline__ ushort f2bf(float f) {  // f32 -> bf16 RNE
  u32 u = __float_as_uint(f);
  u32 r = u + 0x7FFFu + ((u >> 16) & 1u);
  return (ushort)(r >> 16);
}

// ================= fused packing kernel =================
// job A (blocks [0,32768)):   pack adj f32 -> bf16 GEMM A-tile image:
//   chunk (cm=m>>7, s=k>>6) is 16KB, the exact LDS image of one 128x64 tile:
//   unit(16B) = r*8 + (kq ^ (r&7)), r=m&127, kq=(k&63)>>3. The XOR bakes the
//   LDS bank-swizzle into the packed layout so global_load_lds stages linearly.
// job B (blocks [32768,36864)): pack input f32 [8192][1024] -> k-group-major bf16
// job C (blocks [36864,37376)): pack weight f32 [1024][1024] -> k-group-major bf16
__device__ __forceinline__ void packa_body(int idx, const float* __restrict__ A, uint4* __restrict__ out,
                                           int K, int lgS) {
  const int S = K >> 6;
  const int chunk = idx >> 10;
  const int w = idx & 1023;
  const int r = w >> 3, kq = w & 7;
  const int cm = chunk >> lgS, s = chunk & (S - 1);
  const float* src = A + (size_t)((cm << 7) + r) * K + (s << 6) + (kq << 3);
  const float4 f0 = *(const float4*)src;
  const float4 f1 = *(const float4*)(src + 4);
  u32 wv[4];
  wv[0] = (u32)f2bf(f0.x) | ((u32)f2bf(f0.y) << 16);
  wv[1] = (u32)f2bf(f0.z) | ((u32)f2bf(f0.w) << 16);
  wv[2] = (u32)f2bf(f1.x) | ((u32)f2bf(f1.y) << 16);
  wv[3] = (u32)f2bf(f1.z) | ((u32)f2bf(f1.w) << 16);
  uint4 o; o.x = wv[0]; o.y = wv[1]; o.z = wv[2]; o.w = wv[3];
  out[((size_t)chunk << 10) + (r << 3) + (kq ^ (r & 7))] = o;
}

__device__ __forceinline__ void packb_body(int idx, const float* __restrict__ B, uint4* __restrict__ out,
                                           int Nn) {
  const int g = idx / Nn;
  const int n = idx - g * Nn;
  u32 wv[4];
#pragma unroll
  for (int j = 0; j < 4; j++) {
    const float f0 = B[(size_t)(g * 8 + 2 * j) * Nn + n];
    const float f1 = B[(size_t)(g * 8 + 2 * j + 1) * Nn + n];
    wv[j] = (u32)f2bf(f0) | ((u32)f2bf(f1) << 16);
  }
  uint4 o; o.x = wv[0]; o.y = wv[1]; o.z = wv[2]; o.w = wv[3];
  out[idx] = o;
}

__global__ __launch_bounds__(256) void pack_all_k(
    const float* __restrict__ adj, uint4* __restrict__ apk,
    const float* __restrict__ inp, uint4* __restrict__ b1p,
    const float* __restrict__ wgt, uint4* __restrict__ wp) {
  const int b = blockIdx.x;
  const int tid = threadIdx.x;
  if (b < 32768) {
    packa_body(b * 256 + tid, adj, apk, 8192, 7);          // 32768*256 units exactly
  } else if (b < 36864) {
    packb_body((b - 32768) * 256 + tid, inp, b1p, 1024);   // (8192/8)*1024 = 4096*256
  } else {
    packb_body((b - 36864) * 256 + tid, wgt, wp, 1024);    // (1024/8)*1024 = 512*256
  }
}

__global__ __launch_bounds__(256) void minmax2_k(const float* __restrict__ part, int G, float* __restrict__ bnd) {
  __shared__ float slo[256], shi[256];
  const int tid = threadIdx.x;
  float lo = 3.4e38f, hi = -3.4e38f;
  for (int i = tid; i < G; i += 256) { lo = fminf(lo, part[i]); hi = fmaxf(hi, part[G + i]); }
  slo[tid] = lo; shi[tid] = hi; __syncthreads();
  for (int s = 128; s > 0; s >>= 1) {
    if (tid < s) { slo[tid] = fminf(slo[tid], slo[tid + s]); shi[tid] = fmaxf(shi[tid], shi[tid + s]); }
    __syncthreads();
  }
  if (tid == 0) { bnd[0] = slo[0]; bnd[1] = shi[0]; }
}

// ================= bf16 MFMA GEMM — m97 structure =================
// 256 threads / 4 waves, 2x2 wave grid of 64x64 tiles (acc[4][4]), BM=BN=128,
// BK=64, both operands staged via global_load_lds (A pre-packed+swizzled,
// B k-group-major), double-buffered LDS (64KB -> 2 blocks/CU), 1 barrier/step.
__device__ __forceinline__ void gld_lds16(const void* g, void* l) {
  __builtin_amdgcn_global_load_lds((const __attribute__((address_space(1))) void*)g,
                                   (__attribute__((address_space(3))) void*)l, 16, 0, 0);
}

// EPI 1: C = (1-alpha)*acc + alpha*aux, + fused block min/max -> prt
// EPI 2: C = theta*acc + (1-theta)*aux, theta = log(lamda/l + 1)
// Grid: bm = blockIdx&63 (XCD = bm&7), bn = blockIdx>>6 — n-blocks of an A-panel
// share one XCD's L2.
template <int EPI>
__global__ __launch_bounds__(256, 2) void gemm_k(
    const bf16t* __restrict__ Ap, const bf16t* __restrict__ Bp,
    const float* __restrict__ aux, const float* __restrict__ sF,
    const int* __restrict__ sI, float* __restrict__ C,
    float* __restrict__ prt, int PG, int Nn, int K) {
  __shared__ __align__(16) bf16t As[2][8192];
  __shared__ __align__(16) bf16t Bs[2][8192];
  const int tid = threadIdx.x;
  const int lane = tid & 63;
  const int wave = tid >> 6;                 // 0..3
  const int bm = blockIdx.x & 63;
  const int bn = blockIdx.x >> 6;
  const int m0 = bm << 7, n0 = bn << 7;
  const int wm = (wave & 1) << 6;            // 0,64
  const int wn = (wave >> 1) << 6;           // 0,64
  const int S = K >> 6;

  f32x4 acc[4][4];
#pragma unroll
  for (int i = 0; i < 4; i++)
#pragma unroll
    for (int j = 0; j < 4; j++) acc[i][j] = (f32x4){0.f, 0.f, 0.f, 0.f};

  // staging: 1024 16B-units per tile; thread t owns units t + j*256, j=0..3
  const bf16t* gA0 = Ap + (((size_t)bm * S) << 13);  // chunk (bm,s): 8192 bf16
  const bf16t* gBj[4];
  const size_t bstep = (size_t)Nn * 64;              // B elems per super-step
#pragma unroll
  for (int j = 0; j < 4; j++) {
    const int u = tid + (j << 8);
    gBj[j] = Bp + ((size_t)(u >> 7) * Nn + n0 + (u & 127)) * 8;
  }
  auto stage = [&](int s, int buf) {
    const bf16t* a = gA0 + ((size_t)s << 13);
#pragma unroll
    for (int j = 0; j < 4; j++) {
      const int u = tid + (j << 8);
      gld_lds16(a + ((size_t)u << 3), &As[buf][u << 3]);
    }
#pragma unroll
    for (int j = 0; j < 4; j++) {
      const int u = tid + (j << 8);
      gld_lds16(gBj[j] + (size_t)s * bstep, &Bs[buf][u << 3]);
    }
  };

  // frag read bases (bf16-element indices)
  const int arow = lane & 15, aq = lane >> 4;
  // A: elem = row*64 + ((kq ^ (row&7))<<3), row = wm+mt*16+arow, kq = c*4+aq
  const int abase = ((wm + arow) << 6) + ((aq ^ (arow & 7)) << 3);
  // B: elem = (kg*128 + col)*8, kg = c*4+aq, col = wn+nt*16+arow
  const int bbase = ((aq << 7) + wn + arow) << 3;

  stage(0, 0);

  for (int s = 0; s < S; ++s) {
    const int cur = s & 1;
    __syncthreads();  // drains step-s prefetch (vmcnt), publishes buf[cur]
    if (s + 1 < S) stage(s + 1, cur ^ 1);
#pragma unroll
    for (int c = 0; c < 2; ++c) {
      short8 af[4], bv[4];
      const int ab = abase ^ (c << 5);
#pragma unroll
      for (int mt = 0; mt < 4; mt++)
        af[mt] = *(const short8*)(&As[cur][ab + mt * 1024]);
#pragma unroll
      for (int nt = 0; nt < 4; nt++)
        bv[nt] = *(const short8*)(&Bs[cur][bbase + (c << 12) + (nt << 7)]);
#pragma unroll
      for (int mt = 0; mt < 4; mt++)
#pragma unroll
        for (int nt = 0; nt < 4; nt++)
          acc[mt][nt] = __builtin_amdgcn_mfma_f32_16x16x32_bf16(af[mt], bv[nt], acc[mt][nt], 0, 0, 0);
    }
  }

  float p1, p2;
  if (EPI == 1) { const float al = sF[0]; p1 = 1.0f - al; p2 = al; }
  else { const float th = logf(sF[0] / (float)sI[0] + 1.0f); p1 = th; p2 = 1.0f - th; }
  const int col = lane & 15, rq = lane >> 4;
  float vlo = 3.4e38f, vhi = -3.4e38f;
#pragma unroll
  for (int mt = 0; mt < 4; mt++)
#pragma unroll
    for (int nt = 0; nt < 4; nt++)
#pragma unroll
      for (int r = 0; r < 4; r++) {
        const int gm = m0 + wm + mt * 16 + (rq << 2) + r;
        const int gn = n0 + wn + nt * 16 + col;
        const size_t ix = (size_t)gm * Nn + gn;
        const float v = p1 * acc[mt][nt][r] + p2 * aux[ix];
        C[ix] = v;
        if (EPI == 1) { vlo = fminf(vlo, v); vhi = fmaxf(vhi, v); }
      }
  if (EPI == 1) {  // fused block min/max -> partials
    __syncthreads();
    float* red = (float*)&As[0][0];
    red[tid] = vlo; red[256 + tid] = vhi;
    __syncthreads();
    for (int s = 128; s > 0; s >>= 1) {
      if (tid < s) {
        red[tid] = fminf(red[tid], red[tid + s]);
        red[256 + tid] = fmaxf(red[256 + tid], red[256 + tid + s]);
      }
      __syncthreads();
    }
    if (tid == 0) { prt[blockIdx.x] = red[0]; prt[PG + blockIdx.x] = red[256]; }
  }
}

// ================= whale optimizer step =================
// 2048 blocks x 256 threads, ALL co-resident (8 blocks/CU). Wave-per-row
// (4 rows/block), 4 independent float4s in flight per lane, per-lane redundant
// RNG (wave-uniform, no LDS/syncthreads). Explore: 16 ridx then 16 outstanding
// gathers. Final iter writes ONLY the packed-bf16 OPT image (f32 write is dead).
struct WA {
  u32 k1a, k1b, k2a, k2b, k3a, k3b, k4a, k4b, k5a, k5b;
  int ldr;
  float a, a2;
};

__global__ __launch_bounds__(256) void whale_k(
    const float* __restrict__ pinb, float* __restrict__ poutb,
    ushort* __restrict__ opt, const float* __restrict__ bnd, WA w) {
  const int tid = threadIdx.x;
  const int wave = tid >> 6, lane = tid & 63;
  const int row = (blockIdx.x << 2) + wave;
  const float lo = bnd[0], hi = bnd[1];
  // per-row randoms: every lane computes its own copy (wave-uniform values)
  const float r1 = unif_row(w.k1a, w.k1b, row);
  const float r2 = unif_row(w.k2a, w.k2b, row);
  const float u3 = unif_row(w.k3a, w.k3b, row);
  const float p  = unif_row(w.k4a, w.k4b, row);
  // A feeds the |A|>=1 branch decision: match XLA's mul-then-sub (no fma contraction)
  float t2 = (2.0f * w.a) * r1;
  asm volatile("" : "+v"(t2));
  const float A = t2 - w.a;
  const float Cc = 2.0f * r2;
  const float* pin = pinb + ((size_t)row << 10);
  // 4 independent position loads in flight
  float4 pv[4];
#pragma unroll
  for (int k = 0; k < 4; ++k) pv[k] = *(const float4*)(pin + ((lane + (k << 6)) << 2));

  float ov[4][4];
  const bool bp = (p < 0.5f);
  const bool ex = bp && (fabsf(A) >= 1.0f);
  if (ex) {  // explore: per-element random-row gather, 16 loads in flight
    int ri[4][4];
#pragma unroll
    for (int k = 0; k < 4; ++k) {
      const u32 fb = ((u32)row << 10) + (u32)((lane + (k << 6)) << 2);
#pragma unroll
      for (int e = 0; e < 4; ++e) ri[k][e] = ridx_fn(w.k5a, w.k5b, fb + (u32)e);
    }
    float xr[4][4];
#pragma unroll
    for (int k = 0; k < 4; ++k) {
      const int j0 = (lane + (k << 6)) << 2;
#pragma unroll
      for (int e = 0; e < 4; ++e) xr[k][e] = pinb[((size_t)ri[k][e] << 10) + j0 + e];
    }
#pragma unroll
    for (int k = 0; k < 4; ++k)
#pragma unroll
      for (int e = 0; e < 4; ++e) {
        const float pos = (&pv[k].x)[e];
        ov[k][e] = fabsf(xr[k][e] - A * fabsf(Cc * xr[k][e] - pos));
      }
  } else {
    const float* ldp = pinb + ((size_t)w.ldr << 10);
    float4 lv[4];
#pragma unroll
    for (int k = 0; k < 4; ++k) lv[k] = *(const float4*)(ldp + ((lane + (k << 6)) << 2));
    if (bp) {  // exploit
#pragma unroll
      for (int k = 0; k < 4; ++k)
#pragma unroll
        for (int e = 0; e < 4; ++e) {
          const float pos = (&pv[k].x)[e], ld = (&lv[k].x)[e];
          ov[k][e] = fabsf(ld - A * fabsf(Cc * ld - pos));
        }
    } else {  // spiral
      const float lp = (w.a2 - 1.0f) * u3 + 1.0f;
      const float s1 = expf(lp);
      const float s2 = cosf(6.2831855f * lp);
#pragma unroll
      for (int k = 0; k < 4; ++k)
#pragma unroll
        for (int e = 0; e < 4; ++e) {
          const float pos = (&pv[k].x)[e], ld = (&lv[k].x)[e];
          ov[k][e] = fabsf(fabsf(ld - pos) * s1 * s2 + ld);
        }
    }
  }
#pragma unroll
  for (int k = 0; k < 4; ++k) {
    const int j0 = (lane + (k << 6)) << 2;
    float4 res;
#pragma unroll
    for (int e = 0; e < 4; ++e) (&res.x)[e] = fminf(fmaxf(ov[k][e], lo), hi);
    if (!opt) {
      *(float4*)(poutb + ((size_t)row << 10) + j0) = res;
    } else {
      // final positions straight into the packed-A image for gemm_k<2>
      // (K=1024 -> S=16): chunk = (row>>7)*16 + (j0>>6), elem in chunk =
      // (row&127)*64 + ((kq ^ (row&7))<<3) + (j0&7), kq = (j0>>3)&7
      ushort4 o4;
      o4.x = f2bf(res.x); o4.y = f2bf(res.y); o4.z = f2bf(res.z); o4.w = f2bf(res.w);
      const int rw = row & 127;
      const size_t chunk = (size_t)((row >> 7) << 4) + (j0 >> 6);
      ushort* dst = opt + (chunk << 13) + (rw << 6) + ((((j0 >> 3) & 7) ^ (rw & 7)) << 3) + (j0 & 7);
      *(ushort4*)dst = o4;
    }
  }
}

// ================= host =================
extern "C" void kernel_launch(void* const* d_in, const int* in_sizes, int n_in,
                              void* d_out, int out_size, void* d_ws, size_t ws_size,
                              hipStream_t stream) {
  const float* inp = (const float*)d_in[0];   // input  [8192,1024]
  const float* adj = (const float*)d_in[1];   // adj    [8192,8192]
  const float* h0  = (const float*)d_in[2];   // h0     [8192,1024]
  const float* wgt = (const float*)d_in[3];   // weight [1024,1024]
  const float* lam = (const float*)d_in[4];   // lamda scalar
  const float* alp = (const float*)d_in[5];   // alpha scalar
  const int* lint  = (const int*)d_in[6];     // l scalar

  float* outp = (float*)d_out;

  char* ws = (char*)d_ws;
  // Apk (134.2MB) lives at ws+0 and is dead after gemm1; the whale ping/pong and
  // packed OPT overlay it afterwards (stream-ordered, no overlap in time).
  bf16t* Apk  = (bf16t*)(ws);               // 134.2MB packed adj (dead after gemm1)
  float* P0   = (float*)(ws);               // 33.6MB whale ping   (overlays Apk)
  float* P1   = (float*)(ws + 33554432);    // 33.6MB whale pong   (overlays Apk)
  ushort* OPT = (ushort*)(ws + 67108864);   // 16.8MB final positions, packed-A image
  bf16t* B1p  = (bf16t*)(ws + 134217728);   // 16.8MB packed input
  bf16t* Wp   = (bf16t*)(ws + 150994944);   // 2.1MB packed weight
  float* SUP  = (float*)(ws + 153092096);   // 33.6MB support (live to the end)
  float* PRT  = (float*)(ws + 186646528);   // partials (512 lo + 512 hi)
  float* BND  = (float*)(ws + 186662912);   // lower/upper

  // 1) pack adj (A-tile image, swizzled) + input + weight — single kernel
  hipLaunchKernelGGL(pack_all_k, dim3(37376), dim3(256), 0, stream,
                     adj, (uint4*)Apk, inp, (uint4*)B1p, wgt, (uint4*)Wp);
  // 2) support = (1-alpha)*(adj@input) + alpha*h0, + fused min/max partials
  hipLaunchKernelGGL((gemm_k<1>), dim3(512), dim3(256), 0, stream, Apk, B1p, h0, alp, lint,
                     SUP, PRT, 512, 1024, 8192);
  // 3) reduce 512 block partials -> lower/upper
  hipLaunchKernelGGL(minmax2_k, dim3(1), dim3(256), 0, stream, PRT, 512, BND);

  // 4) whale optimizer: key(42) = (0,42); split -> (k0, loop_key)
  u32 k0k[2], lpk[2];
  split2(0u, 42u, k0k, lpk);
  int ldr = scalar_randint8192(k0k[0], k0k[1]);
  const float* cur = SUP;
  float* bufs[2] = {P0, P1};
  for (int it = 0; it < 10; ++it) {
    u32 ka, kb; tf2(lpk[0], lpk[1], 0u, (u32)it, ka, kb);  // fold_in(loop_key, it)
    u32 ks[6][2];
    split6(ka, kb, ks);
    u32 k5A[2], k5B[2];
    split2(ks[4][0], ks[4][1], k5A, k5B);  // randint pre-split: use subkey2
    WA w;
    w.k1a = ks[0][0]; w.k1b = ks[0][1];
    w.k2a = ks[1][0]; w.k2b = ks[1][1];
    w.k3a = ks[2][0]; w.k3b = ks[2][1];
    w.k4a = ks[3][0]; w.k4b = ks[3][1];
    w.k5a = k5B[0];   w.k5b = k5B[1];
    w.ldr = ldr;
    const float itf = (float)it;
    w.a = 2.0f - itf * 0.2f;
    w.a2 = -1.0f + itf * (-0.1f);
    float* nxt = bufs[it & 1];
    hipLaunchKernelGGL(whale_k, dim3(2048), dim3(256), 0, stream, cur, nxt,
                       (it == 9) ? OPT : (ushort*)nullptr, BND, w);
    cur = nxt;
    ldr = scalar_randint8192(ks[5][0], ks[5][1]);  // leader index for next iter
  }
  // 5) out = theta*(opt@weight) + (1-theta)*support
  hipLaunchKernelGGL((gemm_k<2>), dim3(512), dim3(256), 0, stream, (const bf16t*)OPT, Wp, SUP, lam, lint,
                     outp, (float*)nullptr, 0, 1024, 1024);
  (void)in_sizes; (void)n_in; (void)out_size; (void)ws_size;
}

// Round 5
// 857.021 us; speedup vs baseline: 2.3615x; 1.0150x over previous
//
#include <hip/hip_runtime.h>
#include <hip/hip_bf16.h>
#include <stdint.h>
#include <math.h>

typedef uint32_t u32;
typedef __hip_bfloat16 bf16t;
typedef __attribute__((ext_vector_type(8))) short short8;
typedef __attribute__((ext_vector_type(4))) float f32x4;

// JAX PRNG: threefry2x32, jax_threefry_partitionable=True semantics (verified R2):
//   split(key,n)[i] = (o0(key;0,i), o1(key;0,i))
//   random_bits32(key,shape)[f] = o0(key;0,f) ^ o1(key;0,f)
//   randint pre-splits its key, uses subkey2; span 8192 pow2 -> bits & 8191
//   fold_in(key,d) = threefry(key,(0,d))

// ================= threefry2x32 (bit-exact vs JAX) =================
__host__ __device__ __forceinline__ void tf2(u32 k0, u32 k1, u32 c0, u32 c1, u32& o0, u32& o1) {
  const u32 ks2 = k0 ^ k1 ^ 0x1BD11BDAu;
  u32 x0 = c0 + k0, x1 = c1 + k1;
#define TFROT(v,r) (((v)<<(r))|((v)>>(32-(r))))
#define TFR(r) { x0 += x1; x1 = TFROT(x1,r); x1 ^= x0; }
  TFR(13) TFR(15) TFR(26) TFR(6)   x0 += k1;  x1 += ks2 + 1u;
  TFR(17) TFR(29) TFR(16) TFR(24)  x0 += ks2; x1 += k0 + 2u;
  TFR(13) TFR(15) TFR(26) TFR(6)   x0 += k0;  x1 += k1 + 3u;
  TFR(17) TFR(29) TFR(16) TFR(24)  x0 += k1;  x1 += ks2 + 4u;
  TFR(13) TFR(15) TFR(26) TFR(6)   x0 += ks2; x1 += k0 + 5u;
#undef TFR
#undef TFROT
  o0 = x0; o1 = x1;
}

__host__ __device__ __forceinline__ float unif_row(u32 ka, u32 kb, int i) {
  u32 o0, o1;
  tf2(ka, kb, 0u, (u32)i, o0, o1);
  return __uint_as_float(0x3F800000u | ((o0 ^ o1) >> 9)) - 1.0f;
}

__device__ __forceinline__ int ridx_fn(u32 ka, u32 kb, u32 f) {
  u32 o0, o1; tf2(ka, kb, 0u, f, o0, o1); return (int)((o0 ^ o1) & 8191u);
}

static inline void split2(u32 ka, u32 kb, u32* kA, u32* kB) {
  u32 a0, a1, b0, b1;
  tf2(ka, kb, 0u, 0u, a0, a1);
  tf2(ka, kb, 0u, 1u, b0, b1);
  kA[0] = a0; kA[1] = a1; kB[0] = b0; kB[1] = b1;
}

static inline void split6(u32 ka, u32 kb, u32 out[6][2]) {
  for (u32 i = 0; i < 6; i++) { u32 o0, o1; tf2(ka, kb, 0u, i, o0, o1); out[i][0] = o0; out[i][1] = o1; }
}

static inline int scalar_randint8192(u32 ka, u32 kb) {
  u32 kA[2], kB[2];
  split2(ka, kb, kA, kB);
  u32 o0, o1;
  tf2(kB[0], kB[1], 0u, 0u, o0, o1);
  return (int)((o0 ^ o1) & 8191u);
}

__host__ __device__ __forceinline__ ushort f2bf(float f) {  // f32 -> bf16 RNE
  u32 u = __float_as_uint(f);
  u32 r = u + 0x7FFFu + ((u >> 16) & 1u);
  return (ushort)(r >> 16);
}

// ================= fused packing kernel =================
// job A (blocks [0,32768)):   pack adj f32 -> bf16 GEMM A-tile image:
//   chunk (cm=m>>7, s=k>>6) is 16KB, the exact LDS image of one 128x64 tile:
//   unit(16B) = r*8 + (kq ^ (r&7)), r=m&127, kq=(k&63)>>3. The XOR bakes the
//   LDS bank-swizzle into the packed layout so global_load_lds stages linearly.
// job B (blocks [32768,36864)): pack input f32 [8192][1024] -> k-group-major bf16
// job C (blocks [36864,37376)): pack weight f32 [1024][1024] -> k-group-major bf16
__device__ __forceinline__ void packa_body(int idx, const float* __restrict__ A, uint4* __restrict__ out,
                                           int K, int lgS) {
  const int S = K >> 6;
  const int chunk = idx >> 10;
  const int w = idx & 1023;
  const int r = w >> 3, kq = w & 7;
  const int cm = chunk >> lgS, s = chunk & (S - 1);
  const float* src = A + (size_t)((cm << 7) + r) * K + (s << 6) + (kq << 3);
  const float4 f0 = *(const float4*)src;
  const float4 f1 = *(const float4*)(src + 4);
  u32 wv[4];
  wv[0] = (u32)f2bf(f0.x) | ((u32)f2bf(f0.y) << 16);
  wv[1] = (u32)f2bf(f0.z) | ((u32)f2bf(f0.w) << 16);
  wv[2] = (u32)f2bf(f1.x) | ((u32)f2bf(f1.y) << 16);
  wv[3] = (u32)f2bf(f1.z) | ((u32)f2bf(f1.w) << 16);
  uint4 o; o.x = wv[0]; o.y = wv[1]; o.z = wv[2]; o.w = wv[3];
  out[((size_t)chunk << 10) + (r << 3) + (kq ^ (r & 7))] = o;
}

__device__ __forceinline__ void packb_body(int idx, const float* __restrict__ B, uint4* __restrict__ out,
                                           int Nn) {
  const int g = idx / Nn;
  const int n = idx - g * Nn;
  u32 wv[4];
#pragma unroll
  for (int j = 0; j < 4; j++) {
    const float f0 = B[(size_t)(g * 8 + 2 * j) * Nn + n];
    const float f1 = B[(size_t)(g * 8 + 2 * j + 1) * Nn + n];
    wv[j] = (u32)f2bf(f0) | ((u32)f2bf(f1) << 16);
  }
  uint4 o; o.x = wv[0]; o.y = wv[1]; o.z = wv[2]; o.w = wv[3];
  out[idx] = o;
}

__global__ __launch_bounds__(256) void pack_all_k(
    const float* __restrict__ adj, uint4* __restrict__ apk,
    const float* __restrict__ inp, uint4* __restrict__ b1p,
    const float* __restrict__ wgt, uint4* __restrict__ wp) {
  const int b = blockIdx.x;
  const int tid = threadIdx.x;
  if (b < 32768) {
    packa_body(b * 256 + tid, adj, apk, 8192, 7);          // 32768*256 units exactly
  } else if (b < 36864) {
    packb_body((b - 32768) * 256 + tid, inp, b1p, 1024);   // (8192/8)*1024 = 4096*256
  } else {
    packb_body((b - 36864) * 256 + tid, wgt, wp, 1024);    // (1024/8)*1024 = 512*256
  }
}

__global__ __launch_bounds__(256) void minmax2_k(const float* __restrict__ part, int G, float* __restrict__ bnd) {
  __shared__ float slo[256], shi[256];
  const int tid = threadIdx.x;
  float lo = 3.4e38f, hi = -3.4e38f;
  for (int i = tid; i < G; i += 256) { lo = fminf(lo, part[i]); hi = fmaxf(hi, part[G + i]); }
  slo[tid] = lo; shi[tid] = hi; __syncthreads();
  for (int s = 128; s > 0; s >>= 1) {
    if (tid < s) { slo[tid] = fminf(slo[tid], slo[tid + s]); shi[tid] = fmaxf(shi[tid], shi[tid + s]); }
    __syncthreads();
  }
  if (tid == 0) { bnd[0] = slo[0]; bnd[1] = shi[0]; }
}

// ================= bf16 MFMA GEMM — m97 structure =================
// 256 threads / 4 waves, 2x2 wave grid of 64x64 tiles (acc[4][4]), BM=BN=128,
// BK=64, both operands staged via global_load_lds (A pre-packed+swizzled,
// B k-group-major), double-buffered LDS (64KB -> 2 blocks/CU), 1 barrier/step.
__device__ __forceinline__ void gld_lds16(const void* g, void* l) {
  __builtin_amdgcn_global_load_lds((const __attribute__((address_space(1))) void*)g,
                                   (__attribute__((address_space(3))) void*)l, 16, 0, 0);
}

// EPI 1: C = (1-alpha)*acc + alpha*aux, + fused block min/max -> prt
// EPI 2: C = theta*acc + (1-theta)*aux, theta = log(lamda/l + 1)
// Grid: bm = blockIdx&63 (XCD = bm&7), bn = blockIdx>>6 — n-blocks of an A-panel
// share one XCD's L2.
template <int EPI>
__global__ __launch_bounds__(256, 2) void gemm_k(
    const bf16t* __restrict__ Ap, const bf16t* __restrict__ Bp,
    const float* __restrict__ aux, const float* __restrict__ sF,
    const int* __restrict__ sI, float* __restrict__ C,
    float* __restrict__ prt, int PG, int Nn, int K) {
  __shared__ __align__(16) bf16t As[2][8192];
  __shared__ __align__(16) bf16t Bs[2][8192];
  const int tid = threadIdx.x;
  const int lane = tid & 63;
  const int wave = tid >> 6;                 // 0..3
  const int bm = blockIdx.x & 63;
  const int bn = blockIdx.x >> 6;
  const int m0 = bm << 7, n0 = bn << 7;
  const int wm = (wave & 1) << 6;            // 0,64
  const int wn = (wave >> 1) << 6;           // 0,64
  const int S = K >> 6;

  f32x4 acc[4][4];
#pragma unroll
  for (int i = 0; i < 4; i++)
#pragma unroll
    for (int j = 0; j < 4; j++) acc[i][j] = (f32x4){0.f, 0.f, 0.f, 0.f};

  // staging: 1024 16B-units per tile; thread t owns units t + j*256, j=0..3
  const bf16t* gA0 = Ap + (((size_t)bm * S) << 13);  // chunk (bm,s): 8192 bf16
  const bf16t* gBj[4];
  const size_t bstep = (size_t)Nn * 64;              // B elems per super-step
#pragma unroll
  for (int j = 0; j < 4; j++) {
    const int u = tid + (j << 8);
    gBj[j] = Bp + ((size_t)(u >> 7) * Nn + n0 + (u & 127)) * 8;
  }
  auto stage = [&](int s, int buf) {
    const bf16t* a = gA0 + ((size_t)s << 13);
#pragma unroll
    for (int j = 0; j < 4; j++) {
      const int u = tid + (j << 8);
      gld_lds16(a + ((size_t)u << 3), &As[buf][u << 3]);
    }
#pragma unroll
    for (int j = 0; j < 4; j++) {
      const int u = tid + (j << 8);
      gld_lds16(gBj[j] + (size_t)s * bstep, &Bs[buf][u << 3]);
    }
  };

  // frag read bases (bf16-element indices)
  const int arow = lane & 15, aq = lane >> 4;
  // A: elem = row*64 + ((kq ^ (row&7))<<3), row = wm+mt*16+arow, kq = c*4+aq
  const int abase = ((wm + arow) << 6) + ((aq ^ (arow & 7)) << 3);
  // B: elem = (kg*128 + col)*8, kg = c*4+aq, col = wn+nt*16+arow
  const int bbase = ((aq << 7) + wn + arow) << 3;

  stage(0, 0);

  for (int s = 0; s < S; ++s) {
    const int cur = s & 1;
    __syncthreads();  // drains step-s prefetch (vmcnt), publishes buf[cur]
    if (s + 1 < S) stage(s + 1, cur ^ 1);
#pragma unroll
    for (int c = 0; c < 2; ++c) {
      short8 af[4], bv[4];
      const int ab = abase ^ (c << 5);
#pragma unroll
      for (int mt = 0; mt < 4; mt++)
        af[mt] = *(const short8*)(&As[cur][ab + mt * 1024]);
#pragma unroll
      for (int nt = 0; nt < 4; nt++)
        bv[nt] = *(const short8*)(&Bs[cur][bbase + (c << 12) + (nt << 7)]);
#pragma unroll
      for (int mt = 0; mt < 4; mt++)
#pragma unroll
        for (int nt = 0; nt < 4; nt++)
          acc[mt][nt] = __builtin_amdgcn_mfma_f32_16x16x32_bf16(af[mt], bv[nt], acc[mt][nt], 0, 0, 0);
    }
  }

  float p1, p2;
  if (EPI == 1) { const float al = sF[0]; p1 = 1.0f - al; p2 = al; }
  else { const float th = logf(sF[0] / (float)sI[0] + 1.0f); p1 = th; p2 = 1.0f - th; }
  const int col = lane & 15, rq = lane >> 4;
  float vlo = 3.4e38f, vhi = -3.4e38f;
#pragma unroll
  for (int mt = 0; mt < 4; mt++)
#pragma unroll
    for (int nt = 0; nt < 4; nt++)
#pragma unroll
      for (int r = 0; r < 4; r++) {
        const int gm = m0 + wm + mt * 16 + (rq << 2) + r;
        const int gn = n0 + wn + nt * 16 + col;
        const size_t ix = (size_t)gm * Nn + gn;
        const float v = p1 * acc[mt][nt][r] + p2 * aux[ix];
        C[ix] = v;
        if (EPI == 1) { vlo = fminf(vlo, v); vhi = fmaxf(vhi, v); }
      }
  if (EPI == 1) {  // fused block min/max -> partials
    __syncthreads();
    float* red = (float*)&As[0][0];
    red[tid] = vlo; red[256 + tid] = vhi;
    __syncthreads();
    for (int s = 128; s > 0; s >>= 1) {
      if (tid < s) {
        red[tid] = fminf(red[tid], red[tid + s]);
        red[256 + tid] = fmaxf(red[256 + tid], red[256 + tid + s]);
      }
      __syncthreads();
    }
    if (tid == 0) { prt[blockIdx.x] = red[0]; prt[PG + blockIdx.x] = red[256]; }
  }
}

// ================= whale optimizer =================
// Iterations 0..4 (explore reachable): one launch per iteration, 2048 blocks x
// 256 threads, wave-per-row, 4 independent float4s per lane, per-lane redundant
// RNG (wave-uniform). Iterations 5..9: explore is IMPOSSIBLE (it>=6: a<1 in f32
// forces |A|<1; it=5: a==1.0f exactly, explore needs r1==0, host-checked against
// the fixed seed-42 PRNG stream) -> each row depends only on itself + leader
// VALUES. ldrchain_k computes the 5 leader-row values (forward-simulating the
// 4 target rows), then fused5_k applies all 5 updates in registers in ONE pass
// and writes the packed-bf16 OPT image directly. Saves 4 launches + 4x67MB.
struct WA {
  u32 k1a, k1b, k2a, k2b, k3a, k3b, k4a, k4b, k5a, k5b;
  int ldr;
  float a, a2;
};
struct WP { u32 k1a, k1b, k2a, k2b, k3a, k3b, k4a, k4b; float a, a2; int ldr; };
struct F5 { WP w[5]; };

__global__ __launch_bounds__(256) void whale_k(
    const float* __restrict__ pinb, float* __restrict__ poutb,
    ushort* __restrict__ opt, const float* __restrict__ bnd, WA w) {
  const int tid = threadIdx.x;
  const int wave = tid >> 6, lane = tid & 63;
  const int row = (blockIdx.x << 2) + wave;
  const float lo = bnd[0], hi = bnd[1];
  // per-row randoms: every lane computes its own copy (wave-uniform values)
  const float r1 = unif_row(w.k1a, w.k1b, row);
  const float r2 = unif_row(w.k2a, w.k2b, row);
  const float u3 = unif_row(w.k3a, w.k3b, row);
  const float p  = unif_row(w.k4a, w.k4b, row);
  // A feeds the |A|>=1 branch decision: match XLA's mul-then-sub (no fma contraction)
  float t2 = (2.0f * w.a) * r1;
  asm volatile("" : "+v"(t2));
  const float A = t2 - w.a;
  const float Cc = 2.0f * r2;
  const float* pin = pinb + ((size_t)row << 10);
  float4 pv[4];
#pragma unroll
  for (int k = 0; k < 4; ++k) pv[k] = *(const float4*)(pin + ((lane + (k << 6)) << 2));

  float ov[4][4];
  const bool bp = (p < 0.5f);
  const bool ex = bp && (fabsf(A) >= 1.0f);
  if (ex) {  // explore: per-element random-row gather, 16 loads in flight
    int ri[4][4];
#pragma unroll
    for (int k = 0; k < 4; ++k) {
      const u32 fb = ((u32)row << 10) + (u32)((lane + (k << 6)) << 2);
#pragma unroll
      for (int e = 0; e < 4; ++e) ri[k][e] = ridx_fn(w.k5a, w.k5b, fb + (u32)e);
    }
    float xr[4][4];
#pragma unroll
    for (int k = 0; k < 4; ++k) {
      const int j0 = (lane + (k << 6)) << 2;
#pragma unroll
      for (int e = 0; e < 4; ++e) xr[k][e] = pinb[((size_t)ri[k][e] << 10) + j0 + e];
    }
#pragma unroll
    for (int k = 0; k < 4; ++k)
#pragma unroll
      for (int e = 0; e < 4; ++e) {
        const float pos = (&pv[k].x)[e];
        ov[k][e] = fabsf(xr[k][e] - A * fabsf(Cc * xr[k][e] - pos));
      }
  } else {
    const float* ldp = pinb + ((size_t)w.ldr << 10);
    float4 lv[4];
#pragma unroll
    for (int k = 0; k < 4; ++k) lv[k] = *(const float4*)(ldp + ((lane + (k << 6)) << 2));
    if (bp) {  // exploit
#pragma unroll
      for (int k = 0; k < 4; ++k)
#pragma unroll
        for (int e = 0; e < 4; ++e) {
          const float pos = (&pv[k].x)[e], ld = (&lv[k].x)[e];
          ov[k][e] = fabsf(ld - A * fabsf(Cc * ld - pos));
        }
    } else {  // spiral
      const float lp = (w.a2 - 1.0f) * u3 + 1.0f;
      const float s1 = expf(lp);
      const float s2 = cosf(6.2831855f * lp);
#pragma unroll
      for (int k = 0; k < 4; ++k)
#pragma unroll
        for (int e = 0; e < 4; ++e) {
          const float pos = (&pv[k].x)[e], ld = (&lv[k].x)[e];
          ov[k][e] = fabsf(fabsf(ld - pos) * s1 * s2 + ld);
        }
    }
  }
#pragma unroll
  for (int k = 0; k < 4; ++k) {
    const int j0 = (lane + (k << 6)) << 2;
    float4 res;
#pragma unroll
    for (int e = 0; e < 4; ++e) (&res.x)[e] = fminf(fmaxf(ov[k][e], lo), hi);
    if (!opt) {
      *(float4*)(poutb + ((size_t)row << 10) + j0) = res;
    } else {
      ushort4 o4;
      o4.x = f2bf(res.x); o4.y = f2bf(res.y); o4.z = f2bf(res.z); o4.w = f2bf(res.w);
      const int rw = row & 127;
      const size_t chunk = (size_t)((row >> 7) << 4) + (j0 >> 6);
      ushort* dst = opt + (chunk << 13) + (rw << 6) + ((((j0 >> 3) & 7) ^ (rw & 7)) << 3) + (j0 & 7);
      *(ushort4*)dst = o4;
    }
  }
}

// one non-explore update on NK float4s of a row (bit-identical to whale_k's
// exploit/spiral paths; leader values come from lv)
template <int NK>
__device__ __forceinline__ void upd_row(const WP w, int row, float lo, float hi,
                                        const float4* lv, float4* x) {
  const float r1 = unif_row(w.k1a, w.k1b, row);
  const float r2 = unif_row(w.k2a, w.k2b, row);
  const float u3 = unif_row(w.k3a, w.k3b, row);
  const float p  = unif_row(w.k4a, w.k4b, row);
  float t2 = (2.0f * w.a) * r1;
  asm volatile("" : "+v"(t2));
  const float A = t2 - w.a;
  const float Cc = 2.0f * r2;
  const bool bp = (p < 0.5f);
  float s1 = 0.f, s2 = 0.f;
  if (!bp) {
    const float lp = (w.a2 - 1.0f) * u3 + 1.0f;
    s1 = expf(lp);
    s2 = cosf(6.2831855f * lp);
  }
#pragma unroll
  for (int k = 0; k < NK; ++k)
#pragma unroll
    for (int e = 0; e < 4; ++e) {
      const float pos = (&x[k].x)[e], ld = (&lv[k].x)[e];
      const float ov = bp ? fabsf(ld - A * fabsf(Cc * ld - pos))
                          : fabsf(fabsf(ld - pos) * s1 * s2 + ld);
      (&x[k].x)[e] = fminf(fmaxf(ov, lo), hi);
    }
}

// leader-value chain for it=5..9: V[t][1024] = leader VALUE used at it=5+t.
// V[0] = p4[ldr5]; for t>=1, forward-simulate row ldr_{5+t} through its t updates.
__global__ __launch_bounds__(256) void ldrchain_k(
    const float* __restrict__ p4, const float* __restrict__ bnd,
    float* __restrict__ V, F5 f) {
  const int j0 = threadIdx.x << 2;
  const float lo = bnd[0], hi = bnd[1];
  float4 v[5];
  v[0] = *(const float4*)(p4 + ((size_t)f.w[0].ldr << 10) + j0);
  *(float4*)(V + j0) = v[0];
#pragma unroll
  for (int t = 1; t < 5; ++t) {
    const int row = f.w[t].ldr;
    float4 x = *(const float4*)(p4 + ((size_t)row << 10) + j0);
#pragma unroll
    for (int q = 0; q < t; ++q) upd_row<1>(f.w[q], row, lo, hi, &v[q], &x);
    v[t] = x;
    *(float4*)(V + (t << 10) + j0) = x;
  }
}

// iterations 5..9 fused: one read of P(after-4), 5 in-register updates, one
// packed-bf16 OPT write. 2048 blocks x 256, wave-per-row.
__global__ __launch_bounds__(256) void fused5_k(
    const float* __restrict__ p4, const float* __restrict__ V,
    const float* __restrict__ bnd, ushort* __restrict__ opt, F5 f) {
  const int tid = threadIdx.x;
  const int wave = tid >> 6, lane = tid & 63;
  const int row = (blockIdx.x << 2) + wave;
  const float lo = bnd[0], hi = bnd[1];
  const float* pin = p4 + ((size_t)row << 10);
  float4 x[4];
#pragma unroll
  for (int k = 0; k < 4; ++k) x[k] = *(const float4*)(pin + ((lane + (k << 6)) << 2));
#pragma unroll
  for (int it = 0; it < 5; ++it) {
    float4 lv[4];
#pragma unroll
    for (int k = 0; k < 4; ++k)
      lv[k] = *(const float4*)(V + (it << 10) + ((lane + (k << 6)) << 2));
    upd_row<4>(f.w[it], row, lo, hi, lv, x);
  }
#pragma unroll
  for (int k = 0; k < 4; ++k) {
    const int j0 = (lane + (k << 6)) << 2;
    ushort4 o4;
    o4.x = f2bf(x[k].x); o4.y = f2bf(x[k].y); o4.z = f2bf(x[k].z); o4.w = f2bf(x[k].w);
    const int rw = row & 127;
    const size_t chunk = (size_t)((row >> 7) << 4) + (j0 >> 6);
    ushort* dst = opt + (chunk << 13) + (rw << 6) + ((((j0 >> 3) & 7) ^ (rw & 7)) << 3) + (j0 & 7);
    *(ushort4*)dst = o4;
  }
}

// ================= host =================
extern "C" void kernel_launch(void* const* d_in, const int* in_sizes, int n_in,
                              void* d_out, int out_size, void* d_ws, size_t ws_size,
                              hipStream_t stream) {
  const float* inp = (const float*)d_in[0];   // input  [8192,1024]
  const float* adj = (const float*)d_in[1];   // adj    [8192,8192]
  const float* h0  = (const float*)d_in[2];   // h0     [8192,1024]
  const float* wgt = (const float*)d_in[3];   // weight [1024,1024]
  const float* lam = (const float*)d_in[4];   // lamda scalar
  const float* alp = (const float*)d_in[5];   // alpha scalar
  const int* lint  = (const int*)d_in[6];     // l scalar

  float* outp = (float*)d_out;

  char* ws = (char*)d_ws;
  // Apk (134.2MB) lives at ws+0 and is dead after gemm1; the whale ping/pong and
  // packed OPT overlay it afterwards (stream-ordered, no overlap in time).
  bf16t* Apk  = (bf16t*)(ws);               // 134.2MB packed adj (dead after gemm1)
  float* P0   = (float*)(ws);               // 33.6MB whale ping   (overlays Apk)
  float* P1   = (float*)(ws + 33554432);    // 33.6MB whale pong   (overlays Apk)
  ushort* OPT = (ushort*)(ws + 67108864);   // 16.8MB final positions, packed-A image
  bf16t* B1p  = (bf16t*)(ws + 134217728);   // 16.8MB packed input
  bf16t* Wp   = (bf16t*)(ws + 150994944);   // 2.1MB packed weight
  float* SUP  = (float*)(ws + 153092096);   // 33.6MB support (live to the end)
  float* PRT  = (float*)(ws + 186646528);   // partials (512 lo + 512 hi)
  float* BND  = (float*)(ws + 186662912);   // lower/upper
  float* LDRV = (float*)(ws + 186663168);   // 20KB leader values for it=5..9

  // 1) pack adj (A-tile image, swizzled) + input + weight — single kernel
  hipLaunchKernelGGL(pack_all_k, dim3(37376), dim3(256), 0, stream,
                     adj, (uint4*)Apk, inp, (uint4*)B1p, wgt, (uint4*)Wp);
  // 2) support = (1-alpha)*(adj@input) + alpha*h0, + fused min/max partials
  hipLaunchKernelGGL((gemm_k<1>), dim3(512), dim3(256), 0, stream, Apk, B1p, h0, alp, lint,
                     SUP, PRT, 512, 1024, 8192);
  // 3) reduce 512 block partials -> lower/upper
  hipLaunchKernelGGL(minmax2_k, dim3(1), dim3(256), 0, stream, PRT, 512, BND);

  // 4) whale optimizer: key(42) = (0,42); split -> (k0, loop_key)
  u32 k0k[2], lpk[2];
  split2(0u, 42u, k0k, lpk);
  int ldr = scalar_randint8192(k0k[0], k0k[1]);
  WA wa[10];
  for (int it = 0; it < 10; ++it) {
    u32 ka, kb; tf2(lpk[0], lpk[1], 0u, (u32)it, ka, kb);  // fold_in(loop_key, it)
    u32 ks[6][2];
    split6(ka, kb, ks);
    u32 k5A[2], k5B[2];
    split2(ks[4][0], ks[4][1], k5A, k5B);  // randint pre-split: use subkey2
    WA& w = wa[it];
    w.k1a = ks[0][0]; w.k1b = ks[0][1];
    w.k2a = ks[1][0]; w.k2b = ks[1][1];
    w.k3a = ks[2][0]; w.k3b = ks[2][1];
    w.k4a = ks[3][0]; w.k4b = ks[3][1];
    w.k5a = k5B[0];   w.k5b = k5B[1];
    w.ldr = ldr;
    const float itf = (float)it;
    w.a = 2.0f - itf * 0.2f;
    w.a2 = -1.0f + itf * (-0.1f);
    ldr = scalar_randint8192(ks[5][0], ks[5][1]);  // leader index for next iter
  }
  // explore-safety for it=5 (a==1.0f): explore requires r1==0 exactly; it>=6 has
  // a<1 in f32 so |A|<1 always. PRNG stream is seed-fixed -> exact host check.
  bool safe5 = true;
  for (int r = 0; r < 8192 && safe5; ++r) {
    u32 o0, o1; tf2(wa[5].k1a, wa[5].k1b, 0u, (u32)r, o0, o1);
    if (((o0 ^ o1) >> 9) == 0u) safe5 = false;
  }

  // iterations 0..4: per-iteration launches (explore reachable)
  const float* cur = SUP;
  float* bufs[2] = {P0, P1};
  for (int it = 0; it < 5; ++it) {
    float* nxt = bufs[it & 1];
    hipLaunchKernelGGL(whale_k, dim3(2048), dim3(256), 0, stream, cur, nxt,
                       (ushort*)nullptr, BND, wa[it]);
    cur = nxt;
  }
  if (safe5) {
    // iterations 5..9: leader chain + single fused pass -> packed OPT
    F5 f;
    for (int t = 0; t < 5; ++t) {
      const WA& w = wa[5 + t];
      f.w[t].k1a = w.k1a; f.w[t].k1b = w.k1b;
      f.w[t].k2a = w.k2a; f.w[t].k2b = w.k2b;
      f.w[t].k3a = w.k3a; f.w[t].k3b = w.k3b;
      f.w[t].k4a = w.k4a; f.w[t].k4b = w.k4b;
      f.w[t].a = w.a; f.w[t].a2 = w.a2; f.w[t].ldr = w.ldr;
    }
    hipLaunchKernelGGL(ldrchain_k, dim3(1), dim3(256), 0, stream, cur, BND, LDRV, f);
    hipLaunchKernelGGL(fused5_k, dim3(2048), dim3(256), 0, stream, cur, LDRV, BND, OPT, f);
  } else {
    for (int it = 5; it < 10; ++it) {
      float* nxt = bufs[it & 1];
      hipLaunchKernelGGL(whale_k, dim3(2048), dim3(256), 0, stream, cur, nxt,
                         (it == 9) ? OPT : (ushort*)nullptr, BND, wa[it]);
      cur = nxt;
    }
  }
  // 5) out = theta*(opt@weight) + (1-theta)*support
  hipLaunchKernelGGL((gemm_k<2>), dim3(512), dim3(256), 0, stream, (const bf16t*)OPT, Wp, SUP, lam, lint,
                     outp, (float*)nullptr, 0, 1024, 1024);
  (void)in_sizes; (void)n_in; (void)out_size; (void)ws_size;
}